// Round 1
// baseline (209.487 us; speedup 1.0000x reference)
//
#include <hip/hip_runtime.h>
#include <hip/hip_bf16.h>
#include <math.h>

// Problem constants (B,C,H,W,O,K,E) = (8,256,64,64,256,3,3)
// weff[b,o,c,tap] = sum_e gates[b,e]*(experts[e,o,c,tap]+experts[e,o,c+256,tap])
// out[b,o,h,w] = sum_{c,dh,dw} q[b,c,h+dh-1,w+dw-1] * weff[b,o,c,dh*3+dw]
//
// Workspace layout (~27.3 MB):
//   [0)        yctx   : 2048 f32
//   [8192)     logits : 24 f32
//   [16384)    wf     : bf16 [8 b][9 tap][8 ch][256 o][32 c]     (9,437,184 B)  UNSWIZZLED
//   [9453568)  qT     : bf16 [8 b][8 ch][66 hp][66 wp][32 cl']   (17,842,176 B)
// qT cl' swizzle: group' = (cl>>3) ^ ((wp>>1)&3); keeps ds_read_b128 B-fragment
// reads at free 2-way bank conflicts. wf is read global->VGPR (no LDS), so no swizzle.
//
// R1 change: conv was latency-bound (Occupancy 17%, MfmaUtil 28%, HBM 12%).
// Per-wave tile 64o x 64w fixed total waves at 2048 = 2 waves/SIMD. Split the
// W dim across 2x waves: 512-thread blocks, 8 waves of acc[4][2] (64o x 32w),
// same 128o x 2h x 64w block tile, same grid 512, same LDS 33.8 KB
// -> 16 waves/CU (4/SIMD), halved per-wave dependency chain.

typedef __bf16 bf16x8 __attribute__((ext_vector_type(8)));
typedef __bf16 bf16x4 __attribute__((ext_vector_type(4)));
typedef float f32x4 __attribute__((ext_vector_type(4)));

#define AS1 __attribute__((address_space(1)))
#define AS3 __attribute__((address_space(3)))

// ---------------- kernel 1: y_ctx[b,c] = mean_{h,w} y ----------------
__global__ __launch_bounds__(64) void yctx_kernel(const float* __restrict__ y,
                                                  float* __restrict__ yctx) {
  int bc = blockIdx.x;  // b*256 + c
  const float4* p = (const float4*)(y + (size_t)bc * 4096);
  int lane = threadIdx.x;
  float s = 0.f;
  for (int i = lane; i < 1024; i += 64) {
    float4 v = p[i];
    s += v.x + v.y + v.z + v.w;
  }
#pragma unroll
  for (int off = 32; off > 0; off >>= 1) s += __shfl_down(s, off, 64);
  if (lane == 0) yctx[bc] = s * (1.f / 4096.f);
}

// ---------------- kernel 2: logits[b,e] ----------------
__global__ __launch_bounds__(64) void logits_kernel(const float* __restrict__ yctx,
                                                    const float* __restrict__ gw,
                                                    const float* __restrict__ gb,
                                                    float* __restrict__ logits) {
  int be = blockIdx.x;  // b*3 + e
  int b = be / 3, e = be - b * 3;
  int lane = threadIdx.x;
  float s = 0.f;
  for (int c = lane; c < 256; c += 64)
    s += yctx[b * 256 + c] * (gw[c * 3 + e] + gw[(c + 256) * 3 + e]);
#pragma unroll
  for (int off = 32; off > 0; off >>= 1) s += __shfl_down(s, off, 64);
  if (lane == 0) logits[be] = s + gb[e];
}

// ---------------- kernel 3: wf (mixed, folded, bf16, A-ready layout) ----------------
// One block per o. Coalesced float4 loads of the contiguous [512c][9tap] slab,
// fold c/c+256 into LDS, then gate-mix and store (unswizzled).
__global__ __launch_bounds__(256) void wbuild_kernel(const float* __restrict__ experts,
                                                     const float* __restrict__ logits,
                                                     __bf16* __restrict__ wf) {
  int o = blockIdx.x;      // 0..255
  int tid = threadIdx.x;
  __shared__ float sf[3][2304];  // folded experts [e][c*9+tap], c<256 (27.6 KB)
  __shared__ float g[8][3];

#pragma unroll
  for (int e = 0; e < 3; e++) {
    const float4* src = (const float4*)(experts + ((size_t)e * 256 + o) * 4608);
    float4* dstp = (float4*)sf[e];
    for (int i = tid; i < 576; i += 256) {
      float4 a = src[i], bq = src[i + 576];  // +576 f4 = +2304 floats = c+256 half
      float4 r;
      r.x = a.x + bq.x; r.y = a.y + bq.y; r.z = a.z + bq.z; r.w = a.w + bq.w;
      dstp[i] = r;
    }
  }
  if (tid < 8) {
    float l0 = logits[tid * 3 + 0], l1 = logits[tid * 3 + 1], l2 = logits[tid * 3 + 2];
    float m = fmaxf(l0, fmaxf(l1, l2));
    float e0 = __expf(l0 - m), e1 = __expf(l1 - m), e2 = __expf(l2 - m);
    float inv = 1.f / (e0 + e1 + e2);
    g[tid][0] = e0 * inv; g[tid][1] = e1 * inv; g[tid][2] = e2 * inv;
  }
  __syncthreads();

  int cl = tid & 31, ch = tid >> 5;   // c = tid
#pragma unroll 1
  for (int b = 0; b < 8; b++) {
    float g0 = g[b][0], g1 = g[b][1], g2 = g[b][2];
#pragma unroll
    for (int tap = 0; tap < 9; tap++) {
      float v = g0 * sf[0][tid * 9 + tap] + g1 * sf[1][tid * 9 + tap] +
                g2 * sf[2][tid * 9 + tap];
      wf[((((size_t)b * 9 + tap) * 8 + ch) * 256 + o) * 32 + cl] = (__bf16)v;
    }
  }
}

// ---------------- kernel 4: qT (padded, transposed, bf16, B-ready layout) ----------------
__global__ __launch_bounds__(256) void qt_kernel(const float* __restrict__ q,
                                                 __bf16* __restrict__ qT) {
  int bid = blockIdx.x;          // (b*8 + ch)*66 + hp
  int hp = bid % 66;
  int t2 = bid / 66;
  int ch = t2 & 7;
  int b = t2 >> 3;
  __bf16* dst = qT + (((size_t)(b * 8 + ch) * 66 + hp) * 66) * 32;
  int tid = threadIdx.x;
  float4 z4 = {0.f, 0.f, 0.f, 0.f};
  if (hp == 0 || hp == 65) {     // top/bottom zero padding rows: 4224 B
    float4* d4 = (float4*)dst;
    for (int i = tid; i < 264; i += 256) d4[i] = z4;
    return;
  }
  __shared__ float tile2[64][33];  // [w][c]; write banks (w+c)%32 -> free 2-way
  int h = hp - 1;
  {
    int w = tid & 63, ci = tid >> 6;  // ci 0..3
#pragma unroll
    for (int j = 0; j < 8; j++) {
      int c = ci * 8 + j;
      tile2[w][c] = q[(((size_t)b * 256 + ch * 32 + c) * 64 + h) * 64 + w];
    }
  }
  // zero side columns wp=0 / wp=65 (64 B each)
  if (tid < 4) ((float4*)dst)[tid] = z4;
  else if (tid < 8) ((float4*)(dst + 65 * 32))[tid - 4] = z4;
  __syncthreads();

  int a = tid & 7, wsl = tid >> 3;    // a: c-quad, wsl: 0..31 (2 w each)
  int cl4 = a * 4;
#pragma unroll
  for (int k = 0; k < 2; k++) {
    int w = wsl * 2 + k, wp = w + 1;
    int clp4 = (((cl4 >> 3) ^ ((wp >> 1) & 3)) << 3) | (cl4 & 7);
    float v0 = tile2[w][cl4 + 0], v1 = tile2[w][cl4 + 1];
    float v2 = tile2[w][cl4 + 2], v3 = tile2[w][cl4 + 3];
    bf16x4 r = {(__bf16)v0, (__bf16)v1, (__bf16)v2, (__bf16)v3};
    *(bf16x4*)(dst + wp * 32 + clp4) = r;  // 8B store, 8-aligned
  }
}

// ---------------- kernel 5: MFMA conv — 8 waves, acc[4][2], 16 waves/CU ----------------
__global__ __launch_bounds__(512, 4) void conv_kernel(const __bf16* __restrict__ qT,
                                                      const __bf16* __restrict__ wf,
                                                      float* __restrict__ out) {
  __shared__ __align__(16) __bf16 Qlds[2][4 * 66 * 32];  // 2 x 16.9 KB
  const int tid = threadIdx.x;
  const int lane = tid & 63;
  const int wv = tid >> 6;            // 0..7
  const int wm = wv >> 2;             // o half (0/1)
  const int wn = (wv >> 1) & 1;       // h offset (0/1)
  const int wq = wv & 1;              // w half (0/1)
  const int l15 = lane & 15, qd = lane >> 4;

  const int bid = blockIdx.x;
  const int b = bid & 7;            // XCD swizzle: same b -> same XCD (bid%8 heuristic)
  const int rem = bid >> 3;         // 0..63
  const int o0 = (rem >> 5) * 128;
  const int h0 = (rem & 31) * 2;

  f32x4 acc[4][2];
  {
    f32x4 z = {0.f, 0.f, 0.f, 0.f};
#pragma unroll
    for (int i = 0; i < 4; i++)
#pragma unroll
      for (int j = 0; j < 2; j++) acc[i][j] = z;
  }

  const char* qT_b = (const char*)qT + (size_t)b * 8 * 66 * 66 * 32 * 2;
  // A-fragment base: lane reads 16 B at ((o0+wm*64+mi*16+l15)*32 + qd*8)*2
  const char* abase = (const char*)wf + ((size_t)b * 9 * 8 * 256 +
                                         (size_t)(o0 + wm * 64 + l15)) * 64 +
                      (size_t)qd * 16;
  // step (tap,ch) -> byte offset (tap*8+ch)*256*64
  bf16x8 acur[4], anxt[4];

  // ---- prologue: stage Q(ch=0) -> Qlds[0]; load A(tap0,ch0) into regs
  {
    const char* qsrc = qT_b + ((size_t)h0) * 66 * 32 * 2;
    for (int i = tid; i < 1056; i += 512) {
      int ub = i - lane;
      __builtin_amdgcn_global_load_lds((const AS1 void*)(qsrc + ((size_t)i << 4)),
                                       (AS3 void*)((char*)Qlds[0] + ((size_t)ub << 4)),
                                       16, 0, 0);
    }
#pragma unroll
    for (int mi = 0; mi < 4; mi++)
      acur[mi] = *(const bf16x8*)(abase + mi * 1024);
    __syncthreads();  // drain Q0 staging
  }

#pragma unroll 1
  for (int ch = 0; ch < 8; ch++) {
    // prefetch next ch's Q rows into the other buffer — overlaps all 9 taps
    if (ch < 7) {
      const char* qsrc = qT_b + ((size_t)(ch + 1) * 66 + h0) * 66 * 32 * 2;
      char* qdst = (char*)Qlds[(ch + 1) & 1];
      for (int i = tid; i < 1056; i += 512) {
        int ub = i - lane;
        __builtin_amdgcn_global_load_lds((const AS1 void*)(qsrc + ((size_t)i << 4)),
                                         (AS3 void*)(qdst + ((size_t)ub << 4)),
                                         16, 0, 0);
      }
    }
    const char* Qb = (const char*)Qlds[ch & 1];
#pragma unroll
    for (int tap = 0; tap < 9; tap++) {
      // prefetch A for next step (register double-buffer; plain global->VGPR,
      // waited via vmcnt(N) at first use, NOT at any barrier)
      {
        int tapn = (tap == 8) ? 0 : tap + 1;
        int chn = (tap == 8) ? ch + 1 : ch;   // chn==8 on final step: reads into
                                              // qT region (in-bounds), never used
        size_t aoff = ((size_t)(tapn * 8 + chn)) << 14;
#pragma unroll
        for (int mi = 0; mi < 4; mi++)
          anxt[mi] = *(const bf16x8*)(abase + aoff + mi * 1024);
      }
      const int dh = tap / 3, dw = tap - dh * 3;
      const int r = wn + dh;
#pragma unroll
      for (int ni = 0; ni < 2; ni++) {
        int wp = wq * 32 + ni * 16 + l15 + dw;   // 0..65
        int g = (qd ^ ((wp >> 1) & 3)) << 3;
        bf16x8 bfv = *(const bf16x8*)(Qb + ((r * 66 + wp) * 32 + g) * 2);
#pragma unroll
        for (int mi = 0; mi < 4; mi++)
          acc[mi][ni] = __builtin_amdgcn_mfma_f32_16x16x32_bf16(
              acur[mi], bfv, acc[mi][ni], 0, 0, 0);
      }
#pragma unroll
      for (int mi = 0; mi < 4; mi++) acur[mi] = anxt[mi];
    }
    __syncthreads();  // end of ch: Q(ch+1) staged+drained; buffer reuse safe
  }

  // epilogue: C/D layout col = lane&15 (w), row = qd*4+rr (o)
  const int hh = h0 + wn;
#pragma unroll
  for (int mi = 0; mi < 4; mi++) {
    int o = o0 + wm * 64 + mi * 16 + qd * 4;
#pragma unroll
    for (int ni = 0; ni < 2; ni++) {
      int w = wq * 32 + ni * 16 + l15;
#pragma unroll
      for (int rr = 0; rr < 4; rr++)
        out[(((size_t)b * 256 + (o + rr)) * 64 + hh) * 64 + w] = acc[mi][ni][rr];
    }
  }
}

extern "C" void kernel_launch(void* const* d_in, const int* in_sizes, int n_in,
                              void* d_out, int out_size, void* d_ws, size_t ws_size,
                              hipStream_t stream) {
  (void)in_sizes; (void)n_in; (void)out_size; (void)ws_size;
  const float* q = (const float*)d_in[0];
  const float* y = (const float*)d_in[1];
  const float* experts = (const float*)d_in[2];
  const float* gate_w = (const float*)d_in[3];
  const float* gate_b = (const float*)d_in[4];
  float* out = (float*)d_out;

  char* ws = (char*)d_ws;
  float* yctx = (float*)ws;                         // 8 KB
  float* logits = (float*)(ws + 8192);              // 96 B
  __bf16* wf = (__bf16*)(ws + 16384);               // 9,437,184 B
  __bf16* qT = (__bf16*)(ws + 16384 + 9437184);     // 17,842,176 B

  yctx_kernel<<<2048, 64, 0, stream>>>(y, yctx);
  logits_kernel<<<24, 64, 0, stream>>>(yctx, gate_w, gate_b, logits);
  qt_kernel<<<8 * 8 * 66, 256, 0, stream>>>(q, qT);
  wbuild_kernel<<<256, 256, 0, stream>>>(experts, logits, wf);
  conv_kernel<<<512, 512, 0, stream>>>(qT, wf, out);
}

// Round 2
// 178.742 us; speedup vs baseline: 1.1720x; 1.1720x over previous
//
#include <hip/hip_runtime.h>
#include <hip/hip_bf16.h>
#include <math.h>

// Problem constants (B,C,H,W,O,K,E) = (8,256,64,64,256,3,3)
// weff[b,o,c,tap] = sum_e gates[b,e]*(experts[e,o,c,tap]+experts[e,o,c+256,tap])
// out[b,o,h,w] = sum_{c,dh,dw} q[b,c,h+dh-1,w+dw-1] * weff[b,o,c,dh*3+dw]
//
// Workspace layout (~27.3 MB):
//   [0)        yctx   : 2048 f32
//   [8192)     (unused; was logits — now fused into wbuild)
//   [16384)    wf     : bf16 [8 b][9 tap][8 ch][256 o][32 c]     (9,437,184 B)  UNSWIZZLED
//   [9453568)  qT     : bf16 [8 b][8 ch][66 hp][66 wp][32 cl']   (17,842,176 B)
// qT cl' swizzle: group' = (cl>>3) ^ ((wp>>1)&3); keeps ds_read_b128 B-fragment
// reads at free 2-way bank conflicts. wf is read global->VGPR (no LDS), so no swizzle.
//
// R1 post-mortem: 2x waves (acc[4][2], 512 thr) REGRESSED 50->80us: A-load VMEM
// traffic doubled and per-tap latency cover halved. Conv is A-load-latency bound.
// R2: revert to 256-thr acc[4][4]; A prefetch depth 2 (3-phase static register
// rotation, no in-flight copies); A-batch issued BEFORE Q-stage issues each tap;
// Q staging split into two halves (tap0/tap1) so vmcnt in-order retirement never
// makes an A-wait drain a full 16.9 KB Q DMA.

typedef __bf16 bf16x8 __attribute__((ext_vector_type(8)));
typedef __bf16 bf16x4 __attribute__((ext_vector_type(4)));
typedef float f32x4 __attribute__((ext_vector_type(4)));

#define AS1 __attribute__((address_space(1)))
#define AS3 __attribute__((address_space(3)))

// ---------------- kernel 1: y_ctx[b,c] = mean_{h,w} y ----------------
__global__ __launch_bounds__(64) void yctx_kernel(const float* __restrict__ y,
                                                  float* __restrict__ yctx) {
  int bc = blockIdx.x;  // b*256 + c
  const float4* p = (const float4*)(y + (size_t)bc * 4096);
  int lane = threadIdx.x;
  float s = 0.f;
  for (int i = lane; i < 1024; i += 64) {
    float4 v = p[i];
    s += v.x + v.y + v.z + v.w;
  }
#pragma unroll
  for (int off = 32; off > 0; off >>= 1) s += __shfl_down(s, off, 64);
  if (lane == 0) yctx[bc] = s * (1.f / 4096.f);
}

// ---------------- kernel 2: wf (logits+softmax fused; mixed, folded, bf16) ----------------
// One block per o. Logits computed redundantly per block (24 dots of 256 from
// yctx — trivial, L2-hot). Coalesced float4 loads of the contiguous [512c][9tap]
// slab, fold c/c+256 into LDS, then gate-mix and store (unswizzled).
__global__ __launch_bounds__(256) void wbuild_kernel(const float* __restrict__ experts,
                                                     const float* __restrict__ yctx,
                                                     const float* __restrict__ gw,
                                                     const float* __restrict__ gb,
                                                     __bf16* __restrict__ wf) {
  int o = blockIdx.x;      // 0..255
  int tid = threadIdx.x;
  __shared__ float sf[3][2304];  // folded experts [e][c*9+tap], c<256 (27.6 KB)
  __shared__ float lg[8][3];     // logits
  __shared__ float g[8][3];      // gates

  // ---- logits: 8 b-groups of 32 lanes; each lane covers 8 c's for all 3 e
  {
    int lb = tid >> 5, li = tid & 31;
    float p0 = 0.f, p1 = 0.f, p2 = 0.f;
#pragma unroll
    for (int j = 0; j < 8; j++) {
      int c = li + j * 32;
      float yv = yctx[lb * 256 + c];
      p0 += yv * (gw[c * 3 + 0] + gw[(c + 256) * 3 + 0]);
      p1 += yv * (gw[c * 3 + 1] + gw[(c + 256) * 3 + 1]);
      p2 += yv * (gw[c * 3 + 2] + gw[(c + 256) * 3 + 2]);
    }
#pragma unroll
    for (int off = 16; off > 0; off >>= 1) {
      p0 += __shfl_down(p0, off, 32);
      p1 += __shfl_down(p1, off, 32);
      p2 += __shfl_down(p2, off, 32);
    }
    if (li == 0) {
      lg[lb][0] = p0 + gb[0]; lg[lb][1] = p1 + gb[1]; lg[lb][2] = p2 + gb[2];
    }
  }

  // ---- expert staging + fold
#pragma unroll
  for (int e = 0; e < 3; e++) {
    const float4* src = (const float4*)(experts + ((size_t)e * 256 + o) * 4608);
    float4* dstp = (float4*)sf[e];
    for (int i = tid; i < 576; i += 256) {
      float4 a = src[i], bq = src[i + 576];  // +576 f4 = +2304 floats = c+256 half
      float4 r;
      r.x = a.x + bq.x; r.y = a.y + bq.y; r.z = a.z + bq.z; r.w = a.w + bq.w;
      dstp[i] = r;
    }
  }
  __syncthreads();
  if (tid < 8) {
    float l0 = lg[tid][0], l1 = lg[tid][1], l2 = lg[tid][2];
    float m = fmaxf(l0, fmaxf(l1, l2));
    float e0 = __expf(l0 - m), e1 = __expf(l1 - m), e2 = __expf(l2 - m);
    float inv = 1.f / (e0 + e1 + e2);
    g[tid][0] = e0 * inv; g[tid][1] = e1 * inv; g[tid][2] = e2 * inv;
  }
  __syncthreads();

  int cl = tid & 31, ch = tid >> 5;   // c = tid
#pragma unroll 1
  for (int b = 0; b < 8; b++) {
    float g0 = g[b][0], g1 = g[b][1], g2 = g[b][2];
#pragma unroll
    for (int tap = 0; tap < 9; tap++) {
      float v = g0 * sf[0][tid * 9 + tap] + g1 * sf[1][tid * 9 + tap] +
                g2 * sf[2][tid * 9 + tap];
      wf[((((size_t)b * 9 + tap) * 8 + ch) * 256 + o) * 32 + cl] = (__bf16)v;
    }
  }
}

// ---------------- kernel 3: qT (padded, transposed, bf16, B-ready layout) ----------------
__global__ __launch_bounds__(256) void qt_kernel(const float* __restrict__ q,
                                                 __bf16* __restrict__ qT) {
  int bid = blockIdx.x;          // (b*8 + ch)*66 + hp
  int hp = bid % 66;
  int t2 = bid / 66;
  int ch = t2 & 7;
  int b = t2 >> 3;
  __bf16* dst = qT + (((size_t)(b * 8 + ch) * 66 + hp) * 66) * 32;
  int tid = threadIdx.x;
  float4 z4 = {0.f, 0.f, 0.f, 0.f};
  if (hp == 0 || hp == 65) {     // top/bottom zero padding rows: 4224 B
    float4* d4 = (float4*)dst;
    for (int i = tid; i < 264; i += 256) d4[i] = z4;
    return;
  }
  __shared__ float tile2[64][33];  // [w][c]; write banks (w+c)%32 -> free 2-way
  int h = hp - 1;
  {
    int w = tid & 63, ci = tid >> 6;  // ci 0..3
#pragma unroll
    for (int j = 0; j < 8; j++) {
      int c = ci * 8 + j;
      tile2[w][c] = q[(((size_t)b * 256 + ch * 32 + c) * 64 + h) * 64 + w];
    }
  }
  // zero side columns wp=0 / wp=65 (64 B each)
  if (tid < 4) ((float4*)dst)[tid] = z4;
  else if (tid < 8) ((float4*)(dst + 65 * 32))[tid - 4] = z4;
  __syncthreads();

  int a = tid & 7, wsl = tid >> 3;    // a: c-quad, wsl: 0..31 (2 w each)
  int cl4 = a * 4;
#pragma unroll
  for (int k = 0; k < 2; k++) {
    int w = wsl * 2 + k, wp = w + 1;
    int clp4 = (((cl4 >> 3) ^ ((wp >> 1) & 3)) << 3) | (cl4 & 7);
    float v0 = tile2[w][cl4 + 0], v1 = tile2[w][cl4 + 1];
    float v2 = tile2[w][cl4 + 2], v3 = tile2[w][cl4 + 3];
    bf16x4 r = {(__bf16)v0, (__bf16)v1, (__bf16)v2, (__bf16)v3};
    *(bf16x4*)(dst + wp * 32 + clp4) = r;  // 8B store, 8-aligned
  }
}

// ---------------- kernel 4: MFMA conv — depth-2 A prefetch, decoupled Q staging ----------------
__global__ __launch_bounds__(256) void conv_kernel(const __bf16* __restrict__ qT,
                                                   const __bf16* __restrict__ wf,
                                                   float* __restrict__ out) {
  __shared__ __align__(16) __bf16 Qlds[2][4 * 66 * 32];  // 2 x 16.9 KB
  const int tid = threadIdx.x;
  const int lane = tid & 63;
  const int wv = tid >> 6;
  const int wm = wv >> 1, wn = wv & 1;
  const int l15 = lane & 15, qd = lane >> 4;

  const int bid = blockIdx.x;
  const int b = bid & 7;            // XCD swizzle: same b -> same XCD (bid%8 heuristic)
  const int rem = bid >> 3;         // 0..63
  const int o0 = (rem >> 5) * 128;
  const int h0 = (rem & 31) * 2;

  f32x4 acc[4][4];
  {
    f32x4 z = {0.f, 0.f, 0.f, 0.f};
#pragma unroll
    for (int i = 0; i < 4; i++)
#pragma unroll
      for (int j = 0; j < 4; j++) acc[i][j] = z;
  }

  const char* qT_b = (const char*)qT + (size_t)b * 8 * 66 * 66 * 32 * 2;
  // A-fragment base: lane reads 16 B at ((o0+wm*64+mi*16+l15)*32 + qd*8)*2
  const char* abase = (const char*)wf + ((size_t)b * 9 * 8 * 256 +
                                         (size_t)(o0 + wm * 64 + l15)) * 64 +
                      (size_t)qd * 16;
  // step t = ch*9+tap -> byte offset (tap*8+ch)*16384
  // 3-phase A register rotation: tap t consumes areg[t%3], issues A(t+2) into
  // areg[(t+2)%3] (the set freed at t-1). No copies of in-flight registers.
  bf16x8 areg[3][4];

  // ---- prologue: stage Q(ch=0) -> Qlds[0]; load A(0), A(1) into regs
  {
    const char* qsrc = qT_b + ((size_t)h0) * 66 * 32 * 2;
    for (int i = tid; i < 1056; i += 256) {
      int ub = i - lane;
      __builtin_amdgcn_global_load_lds((const AS1 void*)(qsrc + ((size_t)i << 4)),
                                       (AS3 void*)((char*)Qlds[0] + ((size_t)ub << 4)),
                                       16, 0, 0);
    }
#pragma unroll
    for (int mi = 0; mi < 4; mi++) {
      areg[0][mi] = *(const bf16x8*)(abase + mi * 1024);                 // A(0): tap0,ch0
      areg[1][mi] = *(const bf16x8*)(abase + ((size_t)8 << 14) + mi * 1024);  // A(1): tap1,ch0
    }
    __syncthreads();  // drain Q0 staging (A(0),A(1) also drained)
  }

#pragma unroll 1
  for (int ch = 0; ch < 8; ch++) {
    const char* Qb = (const char*)Qlds[ch & 1];
    const char* qsrc_n = qT_b + ((size_t)(ch + 1) * 66 + h0) * 66 * 32 * 2;
    char* qdst_n = (char*)Qlds[(ch + 1) & 1];
#pragma unroll
    for (int tap = 0; tap < 9; tap++) {
      // 1) issue A(t+2) into areg[(tap+2)%3] FIRST (ahead of any Q issues this tap,
      //    so A-waits never queue behind Q DMA issued the same tap)
      {
        int tapn = (tap + 2 >= 9) ? tap - 7 : tap + 2;
        int chn = (tap + 2 >= 9) ? ch + 1 : ch;   // chn==8 on last ch: in-bounds
                                                  // garbage within wf[b], never used
        size_t aoff = ((size_t)(tapn * 8 + chn)) << 14;
#pragma unroll
        for (int mi = 0; mi < 4; mi++)
          areg[(tap + 2) % 3][mi] = *(const bf16x8*)(abase + aoff + mi * 1024);
      }
      // 2) Q staging for ch+1, split in halves at tap0/tap1 (each half retires
      //    within ~2 tap bodies; A-batches issued later never wait on a full DMA)
      if (ch < 7) {
        if (tap == 0) {
          for (int i = tid; i < 512; i += 256) {
            int ub = i - lane;
            __builtin_amdgcn_global_load_lds((const AS1 void*)(qsrc_n + ((size_t)i << 4)),
                                             (AS3 void*)(qdst_n + ((size_t)ub << 4)),
                                             16, 0, 0);
          }
        } else if (tap == 1) {
          for (int i = 512 + tid; i < 1056; i += 256) {
            int ub = i - lane;
            __builtin_amdgcn_global_load_lds((const AS1 void*)(qsrc_n + ((size_t)i << 4)),
                                             (AS3 void*)(qdst_n + ((size_t)ub << 4)),
                                             16, 0, 0);
          }
        }
      }
      // 3) compute with areg[tap%3]
      const int dh = tap / 3, dw = tap - dh * 3;
      const int r = wn + dh;
#pragma unroll
      for (int ni = 0; ni < 4; ni++) {
        int wp = ni * 16 + l15 + dw;   // 0..65
        int g = (qd ^ ((wp >> 1) & 3)) << 3;
        bf16x8 bfv = *(const bf16x8*)(Qb + ((r * 66 + wp) * 32 + g) * 2);
#pragma unroll
        for (int mi = 0; mi < 4; mi++)
          acc[mi][ni] = __builtin_amdgcn_mfma_f32_16x16x32_bf16(
              areg[tap % 3][mi], bfv, acc[mi][ni], 0, 0, 0);
      }
    }
    __syncthreads();  // end of ch: Q(ch+1) staged+drained; buffer reuse safe
  }

  // epilogue: C/D layout col = lane&15 (w), row = qd*4+rr (o)
  const int hh = h0 + wn;
#pragma unroll
  for (int mi = 0; mi < 4; mi++) {
    int o = o0 + wm * 64 + mi * 16 + qd * 4;
#pragma unroll
    for (int ni = 0; ni < 4; ni++) {
      int w = ni * 16 + l15;
#pragma unroll
      for (int rr = 0; rr < 4; rr++)
        out[(((size_t)b * 256 + (o + rr)) * 64 + hh) * 64 + w] = acc[mi][ni][rr];
    }
  }
}

extern "C" void kernel_launch(void* const* d_in, const int* in_sizes, int n_in,
                              void* d_out, int out_size, void* d_ws, size_t ws_size,
                              hipStream_t stream) {
  (void)in_sizes; (void)n_in; (void)out_size; (void)ws_size;
  const float* q = (const float*)d_in[0];
  const float* y = (const float*)d_in[1];
  const float* experts = (const float*)d_in[2];
  const float* gate_w = (const float*)d_in[3];
  const float* gate_b = (const float*)d_in[4];
  float* out = (float*)d_out;

  char* ws = (char*)d_ws;
  float* yctx = (float*)ws;                         // 8 KB
  __bf16* wf = (__bf16*)(ws + 16384);               // 9,437,184 B
  __bf16* qT = (__bf16*)(ws + 16384 + 9437184);     // 17,842,176 B

  yctx_kernel<<<2048, 64, 0, stream>>>(y, yctx);
  qt_kernel<<<8 * 8 * 66, 256, 0, stream>>>(q, qT);
  wbuild_kernel<<<256, 256, 0, stream>>>(experts, yctx, gate_w, gate_b, wf);
  conv_kernel<<<512, 256, 0, stream>>>(qT, wf, out);
}

// Round 3
// 172.182 us; speedup vs baseline: 1.2167x; 1.0381x over previous
//
#include <hip/hip_runtime.h>
#include <hip/hip_bf16.h>
#include <math.h>

// Problem constants (B,C,H,W,O,K,E) = (8,256,64,64,256,3,3)
// weff[b,o,c,tap] = sum_e gates[b,e]*(experts[e,o,c,tap]+experts[e,o,c+256,tap])
// out[b,o,h,w] = sum_{c,dh,dw} q[b,c,h+dh-1,w+dw-1] * weff[b,o,c,dh*3+dw]
//
// Workspace layout (~27.3 MB):
//   [0)        yctx   : 2048 f32
//   [16384)    wf     : bf16 [8 b][9 tap][8 ch][256 o][32 c]     (9,437,184 B)  UNSWIZZLED
//   [9453568)  qT     : bf16 [8 b][8 ch][66 hp][66 wp][32 cl']   (17,842,176 B)
// qT cl' swizzle: group' = (cl>>3) ^ ((wp>>1)&3); keeps ds_read_b128 B-fragment
// reads at free 2-way bank conflicts. wf is read global->VGPR (no LDS), so no swizzle.
//
// R3 changes:
//  (a) total-conv = ~128us constant across R0-R2 => aux kernels are the dominant
//      cost. qt and wbuild are data-independent: FUSED into one prep_kernel
//      (wbuild blocks first) so they overlap instead of serializing.
//  (b) conv: A-stream L2 traffic halved via 4-h blocks: 256 blocks x 8 waves
//      (wm 0/1, wn 0..3), per-wave schedule IDENTICAL to proven R0 (16 MFMA/tap).
//      1 block/CU exactly, zero tail. LDS 50.7 KB (6-row Q tile, double-buffered).

typedef __bf16 bf16x8 __attribute__((ext_vector_type(8)));
typedef __bf16 bf16x4 __attribute__((ext_vector_type(4)));
typedef float f32x4 __attribute__((ext_vector_type(4)));

#define AS1 __attribute__((address_space(1)))
#define AS3 __attribute__((address_space(3)))

// ---------------- kernel 1: y_ctx[b,c] = mean_{h,w} y ----------------
__global__ __launch_bounds__(64) void yctx_kernel(const float* __restrict__ y,
                                                  float* __restrict__ yctx) {
  int bc = blockIdx.x;  // b*256 + c
  const float4* p = (const float4*)(y + (size_t)bc * 4096);
  int lane = threadIdx.x;
  float s = 0.f;
  for (int i = lane; i < 1024; i += 64) {
    float4 v = p[i];
    s += v.x + v.y + v.z + v.w;
  }
#pragma unroll
  for (int off = 32; off > 0; off >>= 1) s += __shfl_down(s, off, 64);
  if (lane == 0) yctx[bc] = s * (1.f / 4096.f);
}

// ---------------- kernel 2: prep = wbuild (blocks 0..255) + qt (blocks 256..4479) ----------------
union PrepSmem {
  struct {
    float sf[3][2304];   // folded experts [e][c*9+tap], c<256 (27.6 KB)
    float lg[8][3];
    float g[8][3];
  } wb;
  float tile2[64][33];   // qt transpose tile [w][c]
};

__global__ __launch_bounds__(256) void prep_kernel(const float* __restrict__ q,
                                                   const float* __restrict__ experts,
                                                   const float* __restrict__ yctx,
                                                   const float* __restrict__ gw,
                                                   const float* __restrict__ gb,
                                                   __bf16* __restrict__ qT,
                                                   __bf16* __restrict__ wf) {
  __shared__ PrepSmem sm;
  int bid = blockIdx.x;
  int tid = threadIdx.x;

  if (bid < 256) {
    // ======== wbuild role: one block per o ========
    int o = bid;

    // logits: 8 b-groups of 32 lanes; each lane covers 8 c's for all 3 e
    {
      int lb = tid >> 5, li = tid & 31;
      float p0 = 0.f, p1 = 0.f, p2 = 0.f;
#pragma unroll
      for (int j = 0; j < 8; j++) {
        int c = li + j * 32;
        float yv = yctx[lb * 256 + c];
        p0 += yv * (gw[c * 3 + 0] + gw[(c + 256) * 3 + 0]);
        p1 += yv * (gw[c * 3 + 1] + gw[(c + 256) * 3 + 1]);
        p2 += yv * (gw[c * 3 + 2] + gw[(c + 256) * 3 + 2]);
      }
#pragma unroll
      for (int off = 16; off > 0; off >>= 1) {
        p0 += __shfl_down(p0, off, 32);
        p1 += __shfl_down(p1, off, 32);
        p2 += __shfl_down(p2, off, 32);
      }
      if (li == 0) {
        sm.wb.lg[lb][0] = p0 + gb[0];
        sm.wb.lg[lb][1] = p1 + gb[1];
        sm.wb.lg[lb][2] = p2 + gb[2];
      }
    }

    // expert staging + c/c+256 fold
#pragma unroll
    for (int e = 0; e < 3; e++) {
      const float4* src = (const float4*)(experts + ((size_t)e * 256 + o) * 4608);
      float4* dstp = (float4*)sm.wb.sf[e];
      for (int i = tid; i < 576; i += 256) {
        float4 a = src[i], bq = src[i + 576];
        float4 r;
        r.x = a.x + bq.x; r.y = a.y + bq.y; r.z = a.z + bq.z; r.w = a.w + bq.w;
        dstp[i] = r;
      }
    }
    __syncthreads();
    if (tid < 8) {
      float l0 = sm.wb.lg[tid][0], l1 = sm.wb.lg[tid][1], l2 = sm.wb.lg[tid][2];
      float m = fmaxf(l0, fmaxf(l1, l2));
      float e0 = __expf(l0 - m), e1 = __expf(l1 - m), e2 = __expf(l2 - m);
      float inv = 1.f / (e0 + e1 + e2);
      sm.wb.g[tid][0] = e0 * inv; sm.wb.g[tid][1] = e1 * inv; sm.wb.g[tid][2] = e2 * inv;
    }
    __syncthreads();

    int cl = tid & 31, ch = tid >> 5;  // c = tid
#pragma unroll 1
    for (int b = 0; b < 8; b++) {
      float g0 = sm.wb.g[b][0], g1 = sm.wb.g[b][1], g2 = sm.wb.g[b][2];
#pragma unroll
      for (int tap = 0; tap < 9; tap++) {
        float v = g0 * sm.wb.sf[0][tid * 9 + tap] + g1 * sm.wb.sf[1][tid * 9 + tap] +
                  g2 * sm.wb.sf[2][tid * 9 + tap];
        wf[((((size_t)b * 9 + tap) * 8 + ch) * 256 + o) * 32 + cl] = (__bf16)v;
      }
    }
    return;
  }

  // ======== qt role: (b*8 + ch)*66 + hp, blocks 256..4479 ========
  int bid2 = bid - 256;
  int hp = bid2 % 66;
  int t2 = bid2 / 66;
  int ch = t2 & 7;
  int b = t2 >> 3;
  __bf16* dst = qT + (((size_t)(b * 8 + ch) * 66 + hp) * 66) * 32;
  float4 z4 = {0.f, 0.f, 0.f, 0.f};
  if (hp == 0 || hp == 65) {  // top/bottom zero padding rows
    float4* d4 = (float4*)dst;
    for (int i = tid; i < 264; i += 256) d4[i] = z4;
    return;
  }
  int h = hp - 1;
  {
    int w = tid & 63, ci = tid >> 6;  // ci 0..3
#pragma unroll
    for (int j = 0; j < 8; j++) {
      int c = ci * 8 + j;
      sm.tile2[w][c] = q[(((size_t)b * 256 + ch * 32 + c) * 64 + h) * 64 + w];
    }
  }
  // zero side columns wp=0 / wp=65
  if (tid < 4) ((float4*)dst)[tid] = z4;
  else if (tid < 8) ((float4*)(dst + 65 * 32))[tid - 4] = z4;
  __syncthreads();

  int a = tid & 7, wsl = tid >> 3;  // a: c-quad, wsl: 0..31 (2 w each)
  int cl4 = a * 4;
#pragma unroll
  for (int k = 0; k < 2; k++) {
    int w = wsl * 2 + k, wp = w + 1;
    int clp4 = (((cl4 >> 3) ^ ((wp >> 1) & 3)) << 3) | (cl4 & 7);
    float v0 = sm.tile2[w][cl4 + 0], v1 = sm.tile2[w][cl4 + 1];
    float v2 = sm.tile2[w][cl4 + 2], v3 = sm.tile2[w][cl4 + 3];
    bf16x4 r = {(__bf16)v0, (__bf16)v1, (__bf16)v2, (__bf16)v3};
    *(bf16x4*)(dst + wp * 32 + clp4) = r;  // 8B store, 8-aligned
  }
}

// ---------------- kernel 3: MFMA conv — 4-h blocks, 8 waves, halved A L2-traffic ----------------
__global__ __launch_bounds__(512, 2) void conv_kernel(const __bf16* __restrict__ qT,
                                                      const __bf16* __restrict__ wf,
                                                      float* __restrict__ out) {
  __shared__ __align__(16) __bf16 Qlds[2][6 * 66 * 32];  // 2 x 25,344 B = 50.7 KB
  const int tid = threadIdx.x;
  const int lane = tid & 63;
  const int wv = tid >> 6;        // 0..7
  const int wm = wv >> 2;         // o half (0/1)
  const int wn = wv & 3;          // h row within block (0..3)
  const int l15 = lane & 15, qd = lane >> 4;

  const int bid = blockIdx.x;
  const int b = bid & 7;          // XCD swizzle: b's wf+qT (~3.4MB) pinned to one XCD L2
  const int rem = bid >> 3;       // 0..31
  const int o0 = (rem >> 4) * 128;
  const int hq = (rem & 15) * 4;  // 4 output rows per block

  f32x4 acc[4][4];
  {
    f32x4 z = {0.f, 0.f, 0.f, 0.f};
#pragma unroll
    for (int i = 0; i < 4; i++)
#pragma unroll
      for (int j = 0; j < 4; j++) acc[i][j] = z;
  }

  const char* qT_b = (const char*)qT + (size_t)b * 8 * 66 * 66 * 32 * 2;
  // A-fragment base: lane reads 16 B at ((o0+wm*64+mi*16+l15)*32 + qd*8)*2
  const char* abase = (const char*)wf + ((size_t)b * 9 * 8 * 256 +
                                         (size_t)(o0 + wm * 64 + l15)) * 64 +
                      (size_t)qd * 16;
  // 3-phase A register rotation: tap t consumes areg[t%3], issues A(t+2).
  bf16x8 areg[3][4];

  // ---- prologue: stage Q(ch=0) rows hq..hq+5 -> Qlds[0]; load A(0), A(1)
  {
    const char* qsrc = qT_b + ((size_t)hq) * 66 * 32 * 2;
    for (int i = tid; i < 1584; i += 512) {
      int ub = i - lane;
      __builtin_amdgcn_global_load_lds((const AS1 void*)(qsrc + ((size_t)i << 4)),
                                       (AS3 void*)((char*)Qlds[0] + ((size_t)ub << 4)),
                                       16, 0, 0);
    }
#pragma unroll
    for (int mi = 0; mi < 4; mi++) {
      areg[0][mi] = *(const bf16x8*)(abase + mi * 1024);                      // (tap0,ch0)
      areg[1][mi] = *(const bf16x8*)(abase + ((size_t)8 << 14) + mi * 1024);  // (tap1,ch0)
    }
    __syncthreads();  // drain Q0 staging
  }

#pragma unroll 1
  for (int ch = 0; ch < 8; ch++) {
    const char* Qb = (const char*)Qlds[ch & 1];
    const char* qsrc_n = qT_b + ((size_t)(ch + 1) * 66 + hq) * 66 * 32 * 2;
    char* qdst_n = (char*)Qlds[(ch + 1) & 1];
#pragma unroll
    for (int tap = 0; tap < 9; tap++) {
      // 1) issue A(t+2) first (ahead of Q issues this tap)
      {
        int tapn = (tap + 2 >= 9) ? tap - 7 : tap + 2;
        int chn = (tap + 2 >= 9) ? ch + 1 : ch;  // chn==8 on last ch: in-bounds garbage, unused
        size_t aoff = ((size_t)(tapn * 8 + chn)) << 14;
#pragma unroll
        for (int mi = 0; mi < 4; mi++)
          areg[(tap + 2) % 3][mi] = *(const bf16x8*)(abase + aoff + mi * 1024);
      }
      // 2) Q staging for ch+1, two halves at tap0/tap1
      if (ch < 7) {
        if (tap == 0) {
          for (int i = tid; i < 792; i += 512) {
            int ub = i - lane;
            __builtin_amdgcn_global_load_lds((const AS1 void*)(qsrc_n + ((size_t)i << 4)),
                                             (AS3 void*)(qdst_n + ((size_t)ub << 4)),
                                             16, 0, 0);
          }
        } else if (tap == 1) {
          for (int i = 792 + tid; i < 1584; i += 512) {
            int ub = i - lane;
            __builtin_amdgcn_global_load_lds((const AS1 void*)(qsrc_n + ((size_t)i << 4)),
                                             (AS3 void*)(qdst_n + ((size_t)ub << 4)),
                                             16, 0, 0);
          }
        }
      }
      // 3) compute with areg[tap%3]
      const int dh = tap / 3, dw = tap - dh * 3;
      const int r = wn + dh;  // 0..5
#pragma unroll
      for (int ni = 0; ni < 4; ni++) {
        int wp = ni * 16 + l15 + dw;  // 0..65
        int g = (qd ^ ((wp >> 1) & 3)) << 3;
        bf16x8 bfv = *(const bf16x8*)(Qb + ((r * 66 + wp) * 32 + g) * 2);
#pragma unroll
        for (int mi = 0; mi < 4; mi++)
          acc[mi][ni] = __builtin_amdgcn_mfma_f32_16x16x32_bf16(
              areg[tap % 3][mi], bfv, acc[mi][ni], 0, 0, 0);
      }
    }
    __syncthreads();  // end of ch: Q(ch+1) staged+drained; buffer reuse safe
  }

  // epilogue: C/D layout col = lane&15 (w), row = qd*4+rr (o)
  const int hh = hq + wn;
#pragma unroll
  for (int mi = 0; mi < 4; mi++) {
    int o = o0 + wm * 64 + mi * 16 + qd * 4;
#pragma unroll
    for (int ni = 0; ni < 4; ni++) {
      int w = ni * 16 + l15;
#pragma unroll
      for (int rr = 0; rr < 4; rr++)
        out[(((size_t)b * 256 + (o + rr)) * 64 + hh) * 64 + w] = acc[mi][ni][rr];
    }
  }
}

extern "C" void kernel_launch(void* const* d_in, const int* in_sizes, int n_in,
                              void* d_out, int out_size, void* d_ws, size_t ws_size,
                              hipStream_t stream) {
  (void)in_sizes; (void)n_in; (void)out_size; (void)ws_size;
  const float* q = (const float*)d_in[0];
  const float* y = (const float*)d_in[1];
  const float* experts = (const float*)d_in[2];
  const float* gate_w = (const float*)d_in[3];
  const float* gate_b = (const float*)d_in[4];
  float* out = (float*)d_out;

  char* ws = (char*)d_ws;
  float* yctx = (float*)ws;                         // 8 KB
  __bf16* wf = (__bf16*)(ws + 16384);               // 9,437,184 B
  __bf16* qT = (__bf16*)(ws + 16384 + 9437184);     // 17,842,176 B

  yctx_kernel<<<2048, 64, 0, stream>>>(y, yctx);
  prep_kernel<<<256 + 4224, 256, 0, stream>>>(q, experts, yctx, gate_w, gate_b, qT, wf);
  conv_kernel<<<256, 512, 0, stream>>>(qT, wf, out);
}

// Round 4
// 170.199 us; speedup vs baseline: 1.2308x; 1.0117x over previous
//
#include <hip/hip_runtime.h>
#include <hip/hip_bf16.h>
#include <math.h>

// Problem constants (B,C,H,W,O,K,E) = (8,256,64,64,256,3,3)
// weff[b,o,c,tap] = sum_e gates[b,e]*(experts[e,o,c,tap]+experts[e,o,c+256,tap])
// out[b,o,h,w] = sum_{c,dh,dw} q[b,c,h+dh-1,w+dw-1] * weff[b,o,c,dh*3+dw]
//
// Workspace layout (~27.3 MB):
//   [0)        yctx   : 2048 f32
//   [16384)    wf     : bf16, per (b,tap,ch) 16KB slab; element (o,c) at byte
//                       (o>>4)*1024 + (c>>3)*256 + (o&15)*16 + (c&7)*2
//                       => conv wave A-load is IDENTITY-ORDER contiguous 1KB
//   [9453568)  qT     : bf16 [8 b][8 ch][66 hp][66 wp][32 cl']   (17,842,176 B)
// qT cl' swizzle: group' = (cl>>3) ^ ((wp>>1)&3); keeps ds_read_b128 B-fragment
// reads at free 2-way bank conflicts.
//
// R4 change: conv time tracked A wave-load COUNT across R0-R3 (2048 waves ~51us,
// 4096 waves ~80us), depth-2 prefetch neutral => A-path is request-throughput
// bound. Old wf layout made each A-load a lane-PERMUTED 1KB gather (16 lines per
// quarter-wave). New layout: lane L reads base+L*16 (identity) => 4x fewer L2
// line-requests. Same bytes, same fragment contents. Conv/wbuild index change only.

typedef __bf16 bf16x8 __attribute__((ext_vector_type(8)));
typedef __bf16 bf16x4 __attribute__((ext_vector_type(4)));
typedef float f32x4 __attribute__((ext_vector_type(4)));

#define AS1 __attribute__((address_space(1)))
#define AS3 __attribute__((address_space(3)))

// ---------------- kernel 1: y_ctx[b,c] = mean_{h,w} y ----------------
__global__ __launch_bounds__(64) void yctx_kernel(const float* __restrict__ y,
                                                  float* __restrict__ yctx) {
  int bc = blockIdx.x;  // b*256 + c
  const float4* p = (const float4*)(y + (size_t)bc * 4096);
  int lane = threadIdx.x;
  float s = 0.f;
  for (int i = lane; i < 1024; i += 64) {
    float4 v = p[i];
    s += v.x + v.y + v.z + v.w;
  }
#pragma unroll
  for (int off = 32; off > 0; off >>= 1) s += __shfl_down(s, off, 64);
  if (lane == 0) yctx[bc] = s * (1.f / 4096.f);
}

// ---------------- kernel 2: prep = wbuild (blocks 0..255) + qt (blocks 256..4479) ----------------
union PrepSmem {
  struct {
    float sf[3][2304];   // folded experts [e][c*9+tap], c<256 (27.6 KB)
    float lg[8][3];
    float g[8][3];
  } wb;
  float tile2[64][33];   // qt transpose tile [w][c]
};

__global__ __launch_bounds__(256) void prep_kernel(const float* __restrict__ q,
                                                   const float* __restrict__ experts,
                                                   const float* __restrict__ yctx,
                                                   const float* __restrict__ gw,
                                                   const float* __restrict__ gb,
                                                   __bf16* __restrict__ qT,
                                                   __bf16* __restrict__ wf) {
  __shared__ PrepSmem sm;
  int bid = blockIdx.x;
  int tid = threadIdx.x;

  if (bid < 256) {
    // ======== wbuild role: one block per o ========
    int o = bid;

    // logits: 8 b-groups of 32 lanes; each lane covers 8 c's for all 3 e
    {
      int lb = tid >> 5, li = tid & 31;
      float p0 = 0.f, p1 = 0.f, p2 = 0.f;
#pragma unroll
      for (int j = 0; j < 8; j++) {
        int c = li + j * 32;
        float yv = yctx[lb * 256 + c];
        p0 += yv * (gw[c * 3 + 0] + gw[(c + 256) * 3 + 0]);
        p1 += yv * (gw[c * 3 + 1] + gw[(c + 256) * 3 + 1]);
        p2 += yv * (gw[c * 3 + 2] + gw[(c + 256) * 3 + 2]);
      }
#pragma unroll
      for (int off = 16; off > 0; off >>= 1) {
        p0 += __shfl_down(p0, off, 32);
        p1 += __shfl_down(p1, off, 32);
        p2 += __shfl_down(p2, off, 32);
      }
      if (li == 0) {
        sm.wb.lg[lb][0] = p0 + gb[0];
        sm.wb.lg[lb][1] = p1 + gb[1];
        sm.wb.lg[lb][2] = p2 + gb[2];
      }
    }

    // expert staging + c/c+256 fold
#pragma unroll
    for (int e = 0; e < 3; e++) {
      const float4* src = (const float4*)(experts + ((size_t)e * 256 + o) * 4608);
      float4* dstp = (float4*)sm.wb.sf[e];
      for (int i = tid; i < 576; i += 256) {
        float4 a = src[i], bq = src[i + 576];
        float4 r;
        r.x = a.x + bq.x; r.y = a.y + bq.y; r.z = a.z + bq.z; r.w = a.w + bq.w;
        dstp[i] = r;
      }
    }
    __syncthreads();
    if (tid < 8) {
      float l0 = sm.wb.lg[tid][0], l1 = sm.wb.lg[tid][1], l2 = sm.wb.lg[tid][2];
      float m = fmaxf(l0, fmaxf(l1, l2));
      float e0 = __expf(l0 - m), e1 = __expf(l1 - m), e2 = __expf(l2 - m);
      float inv = 1.f / (e0 + e1 + e2);
      sm.wb.g[tid][0] = e0 * inv; sm.wb.g[tid][1] = e1 * inv; sm.wb.g[tid][2] = e2 * inv;
    }
    __syncthreads();

    int cl = tid & 31, ch = tid >> 5;  // c = tid = ch*32 + cl
    // new-layout element index (bf16 units) within (b,tap):
    //   ch*8192 + (o>>4)*512 + (cl>>3)*128 + (o&15)*8 + (cl&7)
    size_t lbase = (size_t)ch * 8192 + (size_t)(o >> 4) * 512 +
                   (size_t)((cl >> 3) * 128) + (size_t)((o & 15) * 8) + (cl & 7);
#pragma unroll 1
    for (int b = 0; b < 8; b++) {
      float g0 = sm.wb.g[b][0], g1 = sm.wb.g[b][1], g2 = sm.wb.g[b][2];
#pragma unroll
      for (int tap = 0; tap < 9; tap++) {
        float v = g0 * sm.wb.sf[0][tid * 9 + tap] + g1 * sm.wb.sf[1][tid * 9 + tap] +
                  g2 * sm.wb.sf[2][tid * 9 + tap];
        wf[((size_t)b * 9 + tap) * 65536 + lbase] = (__bf16)v;
      }
    }
    return;
  }

  // ======== qt role: (b*8 + ch)*66 + hp, blocks 256..4479 ========
  int bid2 = bid - 256;
  int hp = bid2 % 66;
  int t2 = bid2 / 66;
  int ch = t2 & 7;
  int b = t2 >> 3;
  __bf16* dst = qT + (((size_t)(b * 8 + ch) * 66 + hp) * 66) * 32;
  float4 z4 = {0.f, 0.f, 0.f, 0.f};
  if (hp == 0 || hp == 65) {  // top/bottom zero padding rows
    float4* d4 = (float4*)dst;
    for (int i = tid; i < 264; i += 256) d4[i] = z4;
    return;
  }
  int h = hp - 1;
  {
    int w = tid & 63, ci = tid >> 6;  // ci 0..3
#pragma unroll
    for (int j = 0; j < 8; j++) {
      int c = ci * 8 + j;
      sm.tile2[w][c] = q[(((size_t)b * 256 + ch * 32 + c) * 64 + h) * 64 + w];
    }
  }
  // zero side columns wp=0 / wp=65
  if (tid < 4) ((float4*)dst)[tid] = z4;
  else if (tid < 8) ((float4*)(dst + 65 * 32))[tid - 4] = z4;
  __syncthreads();

  int a = tid & 7, wsl = tid >> 3;  // a: c-quad, wsl: 0..31 (2 w each)
  int cl4 = a * 4;
#pragma unroll
  for (int k = 0; k < 2; k++) {
    int w = wsl * 2 + k, wp = w + 1;
    int clp4 = (((cl4 >> 3) ^ ((wp >> 1) & 3)) << 3) | (cl4 & 7);
    float v0 = sm.tile2[w][cl4 + 0], v1 = sm.tile2[w][cl4 + 1];
    float v2 = sm.tile2[w][cl4 + 2], v3 = sm.tile2[w][cl4 + 3];
    bf16x4 r = {(__bf16)v0, (__bf16)v1, (__bf16)v2, (__bf16)v3};
    *(bf16x4*)(dst + wp * 32 + clp4) = r;  // 8B store, 8-aligned
  }
}

// ---------------- kernel 3: MFMA conv — 4-h blocks, identity-order A loads ----------------
__global__ __launch_bounds__(512, 2) void conv_kernel(const __bf16* __restrict__ qT,
                                                      const __bf16* __restrict__ wf,
                                                      float* __restrict__ out) {
  __shared__ __align__(16) __bf16 Qlds[2][6 * 66 * 32];  // 2 x 25,344 B = 50.7 KB
  const int tid = threadIdx.x;
  const int lane = tid & 63;
  const int wv = tid >> 6;        // 0..7
  const int wm = wv >> 2;         // o half (0/1)
  const int wn = wv & 3;          // h row within block (0..3)
  const int l15 = lane & 15, qd = lane >> 4;

  const int bid = blockIdx.x;
  const int b = bid & 7;          // XCD swizzle: b's wf+qT (~3.4MB) pinned to one XCD L2
  const int rem = bid >> 3;       // 0..31
  const int o0 = (rem >> 4) * 128;
  const int hq = (rem & 15) * 4;  // 4 output rows per block

  f32x4 acc[4][4];
  {
    f32x4 z = {0.f, 0.f, 0.f, 0.f};
#pragma unroll
    for (int i = 0; i < 4; i++)
#pragma unroll
      for (int j = 0; j < 4; j++) acc[i][j] = z;
  }

  const char* qT_b = (const char*)qT + (size_t)b * 8 * 66 * 66 * 32 * 2;
  // A-fragment base, identity-order layout: lane reads 16 B at
  //   (o0+wm*64)*64 + lane*16  (+ mi*1024 per mi, + (tap*8+ch)*16384 per step)
  const char* abase = (const char*)wf + (size_t)b * 9 * 8 * 16384 +
                      (size_t)(o0 + wm * 64) * 64 + (size_t)lane * 16;
  // 3-phase A register rotation: tap t consumes areg[t%3], issues A(t+2).
  bf16x8 areg[3][4];

  // ---- prologue: stage Q(ch=0) rows hq..hq+5 -> Qlds[0]; load A(0), A(1)
  {
    const char* qsrc = qT_b + ((size_t)hq) * 66 * 32 * 2;
    for (int i = tid; i < 1584; i += 512) {
      int ub = i - lane;
      __builtin_amdgcn_global_load_lds((const AS1 void*)(qsrc + ((size_t)i << 4)),
                                       (AS3 void*)((char*)Qlds[0] + ((size_t)ub << 4)),
                                       16, 0, 0);
    }
#pragma unroll
    for (int mi = 0; mi < 4; mi++) {
      areg[0][mi] = *(const bf16x8*)(abase + mi * 1024);                      // (tap0,ch0)
      areg[1][mi] = *(const bf16x8*)(abase + ((size_t)8 << 14) + mi * 1024);  // (tap1,ch0)
    }
    __syncthreads();  // drain Q0 staging
  }

#pragma unroll 1
  for (int ch = 0; ch < 8; ch++) {
    const char* Qb = (const char*)Qlds[ch & 1];
    const char* qsrc_n = qT_b + ((size_t)(ch + 1) * 66 + hq) * 66 * 32 * 2;
    char* qdst_n = (char*)Qlds[(ch + 1) & 1];
#pragma unroll
    for (int tap = 0; tap < 9; tap++) {
      // 1) issue A(t+2) first (ahead of Q issues this tap)
      {
        int tapn = (tap + 2 >= 9) ? tap - 7 : tap + 2;
        int chn = (tap + 2 >= 9) ? ch + 1 : ch;  // chn==8 on last ch: in-bounds garbage, unused
        size_t aoff = ((size_t)(tapn * 8 + chn)) << 14;
#pragma unroll
        for (int mi = 0; mi < 4; mi++)
          areg[(tap + 2) % 3][mi] = *(const bf16x8*)(abase + aoff + mi * 1024);
      }
      // 2) Q staging for ch+1, two halves at tap0/tap1
      if (ch < 7) {
        if (tap == 0) {
          for (int i = tid; i < 792; i += 512) {
            int ub = i - lane;
            __builtin_amdgcn_global_load_lds((const AS1 void*)(qsrc_n + ((size_t)i << 4)),
                                             (AS3 void*)(qdst_n + ((size_t)ub << 4)),
                                             16, 0, 0);
          }
        } else if (tap == 1) {
          for (int i = 792 + tid; i < 1584; i += 512) {
            int ub = i - lane;
            __builtin_amdgcn_global_load_lds((const AS1 void*)(qsrc_n + ((size_t)i << 4)),
                                             (AS3 void*)(qdst_n + ((size_t)ub << 4)),
                                             16, 0, 0);
          }
        }
      }
      // 3) compute with areg[tap%3]
      const int dh = tap / 3, dw = tap - dh * 3;
      const int r = wn + dh;  // 0..5
#pragma unroll
      for (int ni = 0; ni < 4; ni++) {
        int wp = ni * 16 + l15 + dw;  // 0..65
        int g = (qd ^ ((wp >> 1) & 3)) << 3;
        bf16x8 bfv = *(const bf16x8*)(Qb + ((r * 66 + wp) * 32 + g) * 2);
#pragma unroll
        for (int mi = 0; mi < 4; mi++)
          acc[mi][ni] = __builtin_amdgcn_mfma_f32_16x16x32_bf16(
              areg[tap % 3][mi], bfv, acc[mi][ni], 0, 0, 0);
      }
    }
    __syncthreads();  // end of ch: Q(ch+1) staged+drained; buffer reuse safe
  }

  // epilogue: C/D layout col = lane&15 (w), row = qd*4+rr (o)
  const int hh = hq + wn;
#pragma unroll
  for (int mi = 0; mi < 4; mi++) {
    int o = o0 + wm * 64 + mi * 16 + qd * 4;
#pragma unroll
    for (int ni = 0; ni < 4; ni++) {
      int w = ni * 16 + l15;
#pragma unroll
      for (int rr = 0; rr < 4; rr++)
        out[(((size_t)b * 256 + (o + rr)) * 64 + hh) * 64 + w] = acc[mi][ni][rr];
    }
  }
}

extern "C" void kernel_launch(void* const* d_in, const int* in_sizes, int n_in,
                              void* d_out, int out_size, void* d_ws, size_t ws_size,
                              hipStream_t stream) {
  (void)in_sizes; (void)n_in; (void)out_size; (void)ws_size;
  const float* q = (const float*)d_in[0];
  const float* y = (const float*)d_in[1];
  const float* experts = (const float*)d_in[2];
  const float* gate_w = (const float*)d_in[3];
  const float* gate_b = (const float*)d_in[4];
  float* out = (float*)d_out;

  char* ws = (char*)d_ws;
  float* yctx = (float*)ws;                         // 8 KB
  __bf16* wf = (__bf16*)(ws + 16384);               // 9,437,184 B
  __bf16* qT = (__bf16*)(ws + 16384 + 9437184);     // 17,842,176 B

  yctx_kernel<<<2048, 64, 0, stream>>>(y, yctx);
  prep_kernel<<<256 + 4224, 256, 0, stream>>>(q, experts, yctx, gate_w, gate_b, qT, wf);
  conv_kernel<<<256, 512, 0, stream>>>(qT, wf, out);
}

// Round 5
// 158.388 us; speedup vs baseline: 1.3226x; 1.0746x over previous
//
#include <hip/hip_runtime.h>
#include <hip/hip_bf16.h>
#include <math.h>

// Problem constants (B,C,H,W,O,K,E) = (8,256,64,64,256,3,3)
// weff[b,o,c,tap] = sum_e gates[b,e]*(experts[e,o,c,tap]+experts[e,o,c+256,tap])
// out[b,o,h,w] = sum_{c,dh,dw} q[b,c,h+dh-1,w+dw-1] * weff[b,o,c,dh*3+dw]
//
// Workspace layout (~27.3 MB):
//   [0)        yctx   : 2048 f32
//   [16384)    wf     : bf16, per (b,tap,ch) 16KB slab; element (o,c) at byte
//                       (o>>4)*1024 + ((c&31)>>3)*256 + (o&15)*16 + (c&7)*2
//                       => conv wave A-load is IDENTITY-ORDER contiguous 1KB
//   [9453568)  qT     : bf16 [8 b][8 ch][66 hp][66 wp][32 cl']   (17,842,176 B)
// qT cl' swizzle: group' = (cl>>3) ^ ((wp>>1)&3); keeps ds_read_b128 B-fragment
// reads at free 2-way bank conflicts.
//
// R5: aux kernels (yctx+prep ~85us combined, each ~4-5x over BW roofline) are the
// target; conv (43us) untouched. Evidence: total-conv constant ~127us across
// rounds, and R4's wf-store scatter (16B segments) grew aux by 7us => aux time is
// real and store-pattern sensitive.
//  (a) wbuild re-blocked: (og 0..15) x (chh 0..15) so a wave's lanes cover
//      CONTIGUOUS 512B wf runs; 16B bf16x8 stores, 1 per chunk (was 72 scalar
//      2B stores/thread). Experts staged folded in LDS (stride-145, <=2-way banks).
//  (b) yctx: 256-thr blocks (4x f32x4 loads in flight) + LDS cross-wave reduce.

typedef __bf16 bf16x8 __attribute__((ext_vector_type(8)));
typedef __bf16 bf16x4 __attribute__((ext_vector_type(4)));
typedef float f32x4 __attribute__((ext_vector_type(4)));

#define AS1 __attribute__((address_space(1)))
#define AS3 __attribute__((address_space(3)))

// ---------------- kernel 1: y_ctx[b,c] = mean_{h,w} y ----------------
__global__ __launch_bounds__(256) void yctx_kernel(const float* __restrict__ y,
                                                   float* __restrict__ yctx) {
  int bc = blockIdx.x;  // b*256 + c
  const float4* p = (const float4*)(y + (size_t)bc * 4096);
  int tid = threadIdx.x;
  float s = 0.f;
#pragma unroll
  for (int k = 0; k < 4; k++) {
    float4 v = p[tid + k * 256];
    s += v.x + v.y + v.z + v.w;
  }
#pragma unroll
  for (int off = 32; off > 0; off >>= 1) s += __shfl_down(s, off, 64);
  __shared__ float wsum[4];
  if ((tid & 63) == 0) wsum[tid >> 6] = s;
  __syncthreads();
  if (tid == 0) yctx[bc] = (wsum[0] + wsum[1] + wsum[2] + wsum[3]) * (1.f / 4096.f);
}

// ---------------- kernel 2: prep = wbuild (blocks 0..255) + qt (blocks 256..4479) ----------------
union PrepSmem {
  struct {
    float sfold[3 * 16 * 145];  // folded experts [e*16+ol][cloc*9+tap], stride 145 (27.8 KB)
    float lg[8][3];
    float g[8][3];
  } wb;
  float tile2[64][33];          // qt transpose tile [w][c]
};

__global__ __launch_bounds__(256) void prep_kernel(const float* __restrict__ q,
                                                   const float* __restrict__ experts,
                                                   const float* __restrict__ yctx,
                                                   const float* __restrict__ gw,
                                                   const float* __restrict__ gb,
                                                   __bf16* __restrict__ qT,
                                                   __bf16* __restrict__ wf) {
  __shared__ PrepSmem sm;
  int bid = blockIdx.x;
  int tid = threadIdx.x;

  if (bid < 256) {
    // ======== wbuild role: block = (og, chh); o in [og*16, og*16+16), c in [chh*16, chh*16+16) ========
    int og = bid >> 4, chh = bid & 15;
    int chb = chh >> 1;          // 32-c slab index (c>>5)
    int qb = (chh & 1) * 2;      // c-oct base within slab (0 or 2)

    // logits: 8 b-groups of 32 lanes; each lane covers 8 c's for all 3 e
    {
      int lb = tid >> 5, li = tid & 31;
      float p0 = 0.f, p1 = 0.f, p2 = 0.f;
#pragma unroll
      for (int j = 0; j < 8; j++) {
        int c = li + j * 32;
        float yv = yctx[lb * 256 + c];
        p0 += yv * (gw[c * 3 + 0] + gw[(c + 256) * 3 + 0]);
        p1 += yv * (gw[c * 3 + 1] + gw[(c + 256) * 3 + 1]);
        p2 += yv * (gw[c * 3 + 2] + gw[(c + 256) * 3 + 2]);
      }
#pragma unroll
      for (int off = 16; off > 0; off >>= 1) {
        p0 += __shfl_down(p0, off, 32);
        p1 += __shfl_down(p1, off, 32);
        p2 += __shfl_down(p2, off, 32);
      }
      if (li == 0) {
        sm.wb.lg[lb][0] = p0 + gb[0];
        sm.wb.lg[lb][1] = p1 + gb[1];
        sm.wb.lg[lb][2] = p2 + gb[2];
      }
    }

    // stage folded experts: 48 (e,o) pairs x 36 float4 (lo) + 36 (hi), fold-add
    for (int i = tid; i < 1728; i += 256) {
      int p = i / 36, f = i - p * 36;   // p = e*16 + olp
      int e = p >> 4, olp = p & 15;
      int o = og * 16 + olp;
      const float4* src = (const float4*)experts + ((size_t)(e * 256 + o)) * 1152 + chh * 36;
      float4 lo = src[f], hi = src[f + 576];
      float* dst = &sm.wb.sfold[p * 145 + f * 4];
      dst[0] = lo.x + hi.x; dst[1] = lo.y + hi.y;
      dst[2] = lo.z + hi.z; dst[3] = lo.w + hi.w;
    }
    __syncthreads();
    if (tid < 8) {
      float l0 = sm.wb.lg[tid][0], l1 = sm.wb.lg[tid][1], l2 = sm.wb.lg[tid][2];
      float m = fmaxf(l0, fmaxf(l1, l2));
      float e0 = __expf(l0 - m), e1 = __expf(l1 - m), e2 = __expf(l2 - m);
      float inv = 1.f / (e0 + e1 + e2);
      sm.wb.g[tid][0] = e0 * inv; sm.wb.g[tid][1] = e1 * inv; sm.wb.g[tid][2] = e2 * inv;
    }
    __syncthreads();

    // mix + store: per b, 288 chunk-tasks (9 tap x 32 chunks); chunk = qdl*16+ol;
    // lane-consecutive chunks => contiguous 512B wf segments per half-wave.
#pragma unroll 1
    for (int b = 0; b < 8; b++) {
      float g0 = sm.wb.g[b][0], g1 = sm.wb.g[b][1], g2 = sm.wb.g[b][2];
      for (int i = tid; i < 288; i += 256) {
        int tap = i >> 5, ck = i & 31;
        int qdl = ck >> 4, ol = ck & 15;
        const float* r0 = &sm.wb.sfold[(0 * 16 + ol) * 145 + (qdl * 8) * 9 + tap];
        const float* r1 = &sm.wb.sfold[(1 * 16 + ol) * 145 + (qdl * 8) * 9 + tap];
        const float* r2 = &sm.wb.sfold[(2 * 16 + ol) * 145 + (qdl * 8) * 9 + tap];
        bf16x8 rv;
#pragma unroll
        for (int j = 0; j < 8; j++) {
          float v = g0 * r0[j * 9] + g1 * r1[j * 9] + g2 * r2[j * 9];
          rv[j] = (__bf16)v;
        }
        size_t byteoff = (((size_t)b * 9 + tap) * 8 + chb) * 16384 +
                         (size_t)og * 1024 + (size_t)(qb + qdl) * 256 + (size_t)ol * 16;
        *(bf16x8*)((char*)wf + byteoff) = rv;
      }
    }
    return;
  }

  // ======== qt role: (b*8 + ch)*66 + hp, blocks 256..4479 ========
  int bid2 = bid - 256;
  int hp = bid2 % 66;
  int t2 = bid2 / 66;
  int ch = t2 & 7;
  int b = t2 >> 3;
  __bf16* dst = qT + (((size_t)(b * 8 + ch) * 66 + hp) * 66) * 32;
  float4 z4 = {0.f, 0.f, 0.f, 0.f};
  if (hp == 0 || hp == 65) {  // top/bottom zero padding rows
    float4* d4 = (float4*)dst;
    for (int i = tid; i < 264; i += 256) d4[i] = z4;
    return;
  }
  int h = hp - 1;
  {
    int w = tid & 63, ci = tid >> 6;  // ci 0..3
#pragma unroll
    for (int j = 0; j < 8; j++) {
      int c = ci * 8 + j;
      sm.tile2[w][c] = q[(((size_t)b * 256 + ch * 32 + c) * 64 + h) * 64 + w];
    }
  }
  // zero side columns wp=0 / wp=65
  if (tid < 4) ((float4*)dst)[tid] = z4;
  else if (tid < 8) ((float4*)(dst + 65 * 32))[tid - 4] = z4;
  __syncthreads();

  int a = tid & 7, wsl = tid >> 3;  // a: c-quad, wsl: 0..31 (2 w each)
  int cl4 = a * 4;
#pragma unroll
  for (int k = 0; k < 2; k++) {
    int w = wsl * 2 + k, wp = w + 1;
    int clp4 = (((cl4 >> 3) ^ ((wp >> 1) & 3)) << 3) | (cl4 & 7);
    float v0 = sm.tile2[w][cl4 + 0], v1 = sm.tile2[w][cl4 + 1];
    float v2 = sm.tile2[w][cl4 + 2], v3 = sm.tile2[w][cl4 + 3];
    bf16x4 r = {(__bf16)v0, (__bf16)v1, (__bf16)v2, (__bf16)v3};
    *(bf16x4*)(dst + wp * 32 + clp4) = r;  // 8B store, 8-aligned
  }
}

// ---------------- kernel 3: MFMA conv — 4-h blocks, identity-order A loads (R4, proven) ----------------
__global__ __launch_bounds__(512, 2) void conv_kernel(const __bf16* __restrict__ qT,
                                                      const __bf16* __restrict__ wf,
                                                      float* __restrict__ out) {
  __shared__ __align__(16) __bf16 Qlds[2][6 * 66 * 32];  // 2 x 25,344 B = 50.7 KB
  const int tid = threadIdx.x;
  const int lane = tid & 63;
  const int wv = tid >> 6;        // 0..7
  const int wm = wv >> 2;         // o half (0/1)
  const int wn = wv & 3;          // h row within block (0..3)
  const int l15 = lane & 15, qd = lane >> 4;

  const int bid = blockIdx.x;
  const int b = bid & 7;          // XCD swizzle: b's wf+qT (~3.4MB) pinned to one XCD L2
  const int rem = bid >> 3;       // 0..31
  const int o0 = (rem >> 4) * 128;
  const int hq = (rem & 15) * 4;  // 4 output rows per block

  f32x4 acc[4][4];
  {
    f32x4 z = {0.f, 0.f, 0.f, 0.f};
#pragma unroll
    for (int i = 0; i < 4; i++)
#pragma unroll
      for (int j = 0; j < 4; j++) acc[i][j] = z;
  }

  const char* qT_b = (const char*)qT + (size_t)b * 8 * 66 * 66 * 32 * 2;
  // A-fragment base, identity-order layout: lane reads 16 B at
  //   (o0+wm*64)*64 + lane*16  (+ mi*1024 per mi, + (tap*8+ch)*16384 per step)
  const char* abase = (const char*)wf + (size_t)b * 9 * 8 * 16384 +
                      (size_t)(o0 + wm * 64) * 64 + (size_t)lane * 16;
  // 3-phase A register rotation: tap t consumes areg[t%3], issues A(t+2).
  bf16x8 areg[3][4];

  // ---- prologue: stage Q(ch=0) rows hq..hq+5 -> Qlds[0]; load A(0), A(1)
  {
    const char* qsrc = qT_b + ((size_t)hq) * 66 * 32 * 2;
    for (int i = tid; i < 1584; i += 512) {
      int ub = i - lane;
      __builtin_amdgcn_global_load_lds((const AS1 void*)(qsrc + ((size_t)i << 4)),
                                       (AS3 void*)((char*)Qlds[0] + ((size_t)ub << 4)),
                                       16, 0, 0);
    }
#pragma unroll
    for (int mi = 0; mi < 4; mi++) {
      areg[0][mi] = *(const bf16x8*)(abase + mi * 1024);                      // (tap0,ch0)
      areg[1][mi] = *(const bf16x8*)(abase + ((size_t)8 << 14) + mi * 1024);  // (tap1,ch0)
    }
    __syncthreads();  // drain Q0 staging
  }

#pragma unroll 1
  for (int ch = 0; ch < 8; ch++) {
    const char* Qb = (const char*)Qlds[ch & 1];
    const char* qsrc_n = qT_b + ((size_t)(ch + 1) * 66 + hq) * 66 * 32 * 2;
    char* qdst_n = (char*)Qlds[(ch + 1) & 1];
#pragma unroll
    for (int tap = 0; tap < 9; tap++) {
      // 1) issue A(t+2) first (ahead of Q issues this tap)
      {
        int tapn = (tap + 2 >= 9) ? tap - 7 : tap + 2;
        int chn = (tap + 2 >= 9) ? ch + 1 : ch;  // chn==8 on last ch: in-bounds garbage, unused
        size_t aoff = ((size_t)(tapn * 8 + chn)) << 14;
#pragma unroll
        for (int mi = 0; mi < 4; mi++)
          areg[(tap + 2) % 3][mi] = *(const bf16x8*)(abase + aoff + mi * 1024);
      }
      // 2) Q staging for ch+1, two halves at tap0/tap1
      if (ch < 7) {
        if (tap == 0) {
          for (int i = tid; i < 792; i += 512) {
            int ub = i - lane;
            __builtin_amdgcn_global_load_lds((const AS1 void*)(qsrc_n + ((size_t)i << 4)),
                                             (AS3 void*)(qdst_n + ((size_t)ub << 4)),
                                             16, 0, 0);
          }
        } else if (tap == 1) {
          for (int i = 792 + tid; i < 1584; i += 512) {
            int ub = i - lane;
            __builtin_amdgcn_global_load_lds((const AS1 void*)(qsrc_n + ((size_t)i << 4)),
                                             (AS3 void*)(qdst_n + ((size_t)ub << 4)),
                                             16, 0, 0);
          }
        }
      }
      // 3) compute with areg[tap%3]
      const int dh = tap / 3, dw = tap - dh * 3;
      const int r = wn + dh;  // 0..5
#pragma unroll
      for (int ni = 0; ni < 4; ni++) {
        int wp = ni * 16 + l15 + dw;  // 0..65
        int g = (qd ^ ((wp >> 1) & 3)) << 3;
        bf16x8 bfv = *(const bf16x8*)(Qb + ((r * 66 + wp) * 32 + g) * 2);
#pragma unroll
        for (int mi = 0; mi < 4; mi++)
          acc[mi][ni] = __builtin_amdgcn_mfma_f32_16x16x32_bf16(
              areg[tap % 3][mi], bfv, acc[mi][ni], 0, 0, 0);
      }
    }
    __syncthreads();  // end of ch: Q(ch+1) staged+drained; buffer reuse safe
  }

  // epilogue: C/D layout col = lane&15 (w), row = qd*4+rr (o)
  const int hh = hq + wn;
#pragma unroll
  for (int mi = 0; mi < 4; mi++) {
    int o = o0 + wm * 64 + mi * 16 + qd * 4;
#pragma unroll
    for (int ni = 0; ni < 4; ni++) {
      int w = ni * 16 + l15;
#pragma unroll
      for (int rr = 0; rr < 4; rr++)
        out[(((size_t)b * 256 + (o + rr)) * 64 + hh) * 64 + w] = acc[mi][ni][rr];
    }
  }
}

extern "C" void kernel_launch(void* const* d_in, const int* in_sizes, int n_in,
                              void* d_out, int out_size, void* d_ws, size_t ws_size,
                              hipStream_t stream) {
  (void)in_sizes; (void)n_in; (void)out_size; (void)ws_size;
  const float* q = (const float*)d_in[0];
  const float* y = (const float*)d_in[1];
  const float* experts = (const float*)d_in[2];
  const float* gate_w = (const float*)d_in[3];
  const float* gate_b = (const float*)d_in[4];
  float* out = (float*)d_out;

  char* ws = (char*)d_ws;
  float* yctx = (float*)ws;                         // 8 KB
  __bf16* wf = (__bf16*)(ws + 16384);               // 9,437,184 B
  __bf16* qT = (__bf16*)(ws + 16384 + 9437184);     // 17,842,176 B

  yctx_kernel<<<2048, 256, 0, stream>>>(y, yctx);
  prep_kernel<<<256 + 4224, 256, 0, stream>>>(q, experts, yctx, gate_w, gate_b, qT, wf);
  conv_kernel<<<256, 512, 0, stream>>>(qT, wf, out);
}